// Round 2
// baseline (293.583 us; speedup 1.0000x reference)
//
#include <hip/hip_runtime.h>

// GatedCrossModalAttention: B=16384, NM=5, D=256, H=8. FP32 I/O, bf16 internal.
// Attention collapses (Lq=Lk=1 => softmax==1):
//   branch_s(x) = x[:,mod_s] @ (Wo_s@Wv_s)^T + (Wo_s@bv_s+bo_s).
// K1: fuse weights -> WF bf16 [5][256][256] ([out][in]), BF f32 [5][256]  (660 KB ws ONLY)
// Round-2 lesson: 43 MB Y workspace overflowed ws_size and corrupted pristine inputs.
// Round-3 lesson: widening blocks (4->8 waves, same 512-block grid) raised occupancy
// 21->41% but only -8% time: the limiter is the per-block serial phase chain with
// just 2 chains/CU, not raw wave count.
// Round-4 (this): 16 rows/block, 256 thr, grid 1024 -> 4 blocks/CU (4 chains);
// T14 async stage (loads issued at loop top, LDS write just before barrier,
// double-buffered A); epilogue directly on MFMA accumulator in f32 (no Yb bf16
// park, no 64-lane wred ladders; 16-lane shfl + tiny LDS cross-wave exchange).

typedef __attribute__((ext_vector_type(8))) short short8;
typedef __attribute__((ext_vector_type(4))) float floatx4;

__device__ __forceinline__ float b2f(unsigned short h) {
    union { unsigned int u; float f; } v; v.u = ((unsigned int)h) << 16; return v.f;
}
__device__ __forceinline__ unsigned short f2b(float f) {
    union { unsigned int u; float f; } v; v.f = f;
    unsigned int u = v.u;
    return (unsigned short)((u + 0x7FFFu + ((u >> 16) & 1u)) >> 16);
}

// ---------------- K1: weight fusion ----------------
// grid (64, 5), block 256. Each block: 4 output rows of one branch.
__global__ __launch_bounds__(256) void k_fuse(
    const float* __restrict__ sWi, const float* __restrict__ sbi,
    const float* __restrict__ sWo, const float* __restrict__ sbo,
    const float* __restrict__ cWi, const float* __restrict__ cbi,
    const float* __restrict__ cWo, const float* __restrict__ cbo,
    unsigned short* __restrict__ WF, float* __restrict__ BF)
{
    int s = blockIdx.y;
    int i0 = blockIdx.x * 4;
    int tid = threadIdx.x;
    const float *Wo, *Wv, *bv, *bo;
    if (s == 0) { Wo = sWo; Wv = sWi + 512 * 256; bv = sbi + 512; bo = sbo; }
    else {
        int n = s - 1;
        Wo = cWo + n * 65536;
        Wv = cWi + n * 768 * 256 + 512 * 256;
        bv = cbi + n * 768 + 512;
        bo = cbo + n * 256;
    }
    __shared__ float wo[4 * 256];
    #pragma unroll
    for (int it = 0; it < 4; ++it) {
        int idx = tid + it * 256;
        wo[idx] = Wo[i0 * 256 + idx];
    }
    __syncthreads();
    float a0 = 0.f, a1 = 0.f, a2 = 0.f, a3 = 0.f;
    #pragma unroll 8
    for (int k = 0; k < 256; ++k) {
        float wv = Wv[k * 256 + tid];
        a0 += wo[k] * wv;
        a1 += wo[256 + k] * wv;
        a2 += wo[512 + k] * wv;
        a3 += wo[768 + k] * wv;
    }
    unsigned short* dst = WF + ((size_t)s * 256 + i0) * 256 + tid;
    dst[0] = f2b(a0); dst[256] = f2b(a1); dst[512] = f2b(a2); dst[768] = f2b(a3);
    // bias: one wave per output row, lane l covers k=4l..4l+3
    int wv_ = tid >> 6, ln = tid & 63;
    float p = 0.f;
    #pragma unroll
    for (int u = 0; u < 4; ++u) {
        int k = ln * 4 + u;
        p += wo[wv_ * 256 + k] * bv[k];
    }
    #pragma unroll
    for (int o = 32; o > 0; o >>= 1) p += __shfl_xor(p, o, 64);
    if (ln == 0) BF[s * 256 + i0 + wv_] = p + bo[i0 + wv_];
}

// ---------------- K2: fused GEMM + epilogue ----------------
#define ASTR 280   // shorts; 560 B row stride: 16B-aligned, <=2-way LDS bank alias

// grid 1024, block 256 (4 waves). Block: rows [b0, b0+16). Wave w: cols [w*64, w*64+64).
// Per lane: rows q4*4+i (i=0..3), cols w*64+ct*16+l16 (ct=0..3)  [MFMA C-layout].
__global__ __launch_bounds__(256, 4) void k_main(
    const float* __restrict__ x, const unsigned short* __restrict__ WF,
    const float* __restrict__ BF,
    const float* __restrict__ cln_g, const float* __restrict__ cln_b,
    const float* __restrict__ gln_g, const float* __restrict__ gln_b,
    const float* __restrict__ gW, const float* __restrict__ gb,
    const float* __restrict__ fln_g, const float* __restrict__ fln_b,
    const int* __restrict__ midx, float* __restrict__ out)
{
    __shared__ __align__(16) unsigned short Ab[2][16 * ASTR]; // double-buffered A-tile (bf16)
    __shared__ float2 st2[16 * 4];   // (s1,s2) per row per wave
    __shared__ float stN[5][16 * 4]; // gate-logit partials per n,row,wave
    __shared__ float gLDS[16 * 8];   // final gates per row (stride 8)

    const int m = midx[0];
    const int b0 = blockIdx.x * 16;
    const int tid = threadIdx.x;
    const int wave = tid >> 6, lane = tid & 63;
    const int l16 = lane & 15, q4 = lane >> 4;
    const int colb = wave * 64;

    // ---- stage s=0 A-tile loads (issue early) ----
    float4 sreg[4];
    #pragma unroll
    for (int it = 0; it < 4; ++it) {
        int c = tid + it * 256;               // c in float4 units; 64 per row
        sreg[it] = *(const float4*)(x + ((size_t)(b0 + (c >> 6)) * 5 + m) * 256 + ((c & 63) << 2));
    }

    // ---- q (f32, epilogue layout) + per-col gate-LN params ----
    float qv[4][4];
    #pragma unroll
    for (int i = 0; i < 4; ++i)
        #pragma unroll
        for (int ct = 0; ct < 4; ++ct)
            qv[i][ct] = x[((size_t)(b0 + q4 * 4 + i) * 5 + m) * 256 + colb + ct * 16 + l16];
    float glgv[4], glbv[4];
    #pragma unroll
    for (int ct = 0; ct < 4; ++ct) {
        glgv[ct] = gln_g[colb + ct * 16 + l16];
        glbv[ct] = gln_b[colb + ct * 16 + l16];
    }

    // ---- write A buf0 ----
    #pragma unroll
    for (int it = 0; it < 4; ++it) {
        int c = tid + it * 256;
        float4 v = sreg[it];
        uint2 p;
        p.x = (unsigned int)f2b(v.x) | ((unsigned int)f2b(v.y) << 16);
        p.y = (unsigned int)f2b(v.z) | ((unsigned int)f2b(v.w) << 16);
        *(uint2*)(&Ab[0][(c >> 6) * ASTR + ((c & 63) << 2)]) = p;
    }
    __syncthreads();  // buf0 ready

    // ---- gates ----
    // LN(q) stats: wave-local (16-lane groups), then cross-wave via st2
    #pragma unroll
    for (int i = 0; i < 4; ++i) {
        float p1 = qv[i][0] + qv[i][1] + qv[i][2] + qv[i][3];
        float p2 = qv[i][0]*qv[i][0] + qv[i][1]*qv[i][1] + qv[i][2]*qv[i][2] + qv[i][3]*qv[i][3];
        #pragma unroll
        for (int o = 1; o < 16; o <<= 1) { p1 += __shfl_xor(p1, o, 64); p2 += __shfl_xor(p2, o, 64); }
        if (l16 == 0) st2[(q4 * 4 + i) * 4 + wave] = make_float2(p1, p2);
    }
    __syncthreads();
    float qln[4][4];
    #pragma unroll
    for (int i = 0; i < 4; ++i) {
        float s1 = 0.f, s2 = 0.f;
        #pragma unroll
        for (int w2 = 0; w2 < 4; ++w2) { float2 v = st2[(q4 * 4 + i) * 4 + w2]; s1 += v.x; s2 += v.y; }
        float mn = s1 * (1.f / 256.f);
        float vr = s2 * (1.f / 256.f) - mn * mn;
        float rs = rsqrtf(vr + 1e-5f);
        #pragma unroll
        for (int ct = 0; ct < 4; ++ct) qln[i][ct] = (qv[i][ct] - mn) * rs * glgv[ct] + glbv[ct];
    }
    #pragma unroll
    for (int n = 0; n < 5; ++n) {
        float pg[4];
        #pragma unroll
        for (int i = 0; i < 4; ++i) {
            float acc = 0.f;
            #pragma unroll
            for (int ct = 0; ct < 4; ++ct) acc += qln[i][ct] * gW[n * 256 + colb + ct * 16 + l16];
            #pragma unroll
            for (int o = 1; o < 16; o <<= 1) acc += __shfl_xor(acc, o, 64);
            pg[i] = acc;
        }
        if (l16 == 0) {
            #pragma unroll
            for (int i = 0; i < 4; ++i) stN[n][(q4 * 4 + i) * 4 + wave] = pg[i];
        }
    }
    __syncthreads();
    if (wave == 0 && lane < 16) {
        int r = lane;
        float g[5];
        #pragma unroll
        for (int n = 0; n < 5; ++n) {
            float sum = gb[n];
            #pragma unroll
            for (int w2 = 0; w2 < 4; ++w2) sum += stN[n][r * 4 + w2];
            g[n] = sum;
        }
        float mx = g[0];
        #pragma unroll
        for (int n = 1; n < 5; ++n) mx = fmaxf(mx, g[n]);
        float es = 0.f;
        #pragma unroll
        for (int n = 0; n < 5; ++n) { g[n] = __expf(g[n] - mx); es += g[n]; }
        float inv = 1.f / es;
        #pragma unroll
        for (int n = 0; n < 5; ++n) gLDS[r * 8 + n] = g[n] * inv;
    }
    __syncthreads();  // gLDS ready

    // ---- main loop over 5 branches ----
    float comb[4][4];
    #pragma unroll
    for (int i = 0; i < 4; ++i)
        #pragma unroll
        for (int ct = 0; ct < 4; ++ct) comb[i][ct] = 0.f;

    int cur = 0;
    for (int s = 0; s < 5; ++s) {
        // per-s per-col params (issue early, off the inter-barrier path)
        float bfv[4], cgv[4], cbv[4], gsv[4];
        #pragma unroll
        for (int ct = 0; ct < 4; ++ct) {
            int col = colb + ct * 16 + l16;
            bfv[ct] = BF[s * 256 + col];
            if (s > 0) {
                cgv[ct] = cln_g[(s - 1) * 256 + col];
                cbv[ct] = cln_b[(s - 1) * 256 + col];
            } else { cgv[ct] = 0.f; cbv[ct] = 0.f; }
        }
        #pragma unroll
        for (int i = 0; i < 4; ++i) gsv[i] = gLDS[(q4 * 4 + i) * 8 + s];

        // issue next-modal stage loads (hide HBM latency under GEMM)
        float4 nreg[4];
        if (s < 4) {
            int nmod = (s < m) ? s : s + 1;   // modal of branch s+1
            #pragma unroll
            for (int it = 0; it < 4; ++it) {
                int c = tid + it * 256;
                nreg[it] = *(const float4*)(x + ((size_t)(b0 + (c >> 6)) * 5 + nmod) * 256 + ((c & 63) << 2));
            }
        }

        // GEMM: 16x256 = A(16x256) * WF_s^T, wave covers 64 cols
        floatx4 acc[4];
        #pragma unroll
        for (int ct = 0; ct < 4; ++ct) acc[ct] = (floatx4){0.f, 0.f, 0.f, 0.f};
        const unsigned short* wB = WF + (size_t)s * 65536;
        #pragma unroll
        for (int kk = 0; kk < 8; ++kk) {
            int k = kk * 32 + q4 * 8;
            short8 a = *(const short8*)(&Ab[cur][l16 * ASTR + k]);
            #pragma unroll
            for (int ct = 0; ct < 4; ++ct) {
                short8 bb = *(const short8*)(wB + (size_t)(colb + ct * 16 + l16) * 256 + k);
                acc[ct] = __builtin_amdgcn_mfma_f32_16x16x32_bf16(a, bb, acc[ct], 0, 0, 0);
            }
        }

        // t = (s==0 ? y+bf : q+y+bf); wave-local stats for s>=1
        float tv[4][4];
        if (s == 0) {
            #pragma unroll
            for (int i = 0; i < 4; ++i)
                #pragma unroll
                for (int ct = 0; ct < 4; ++ct) tv[i][ct] = acc[ct][i] + bfv[ct];
        } else {
            #pragma unroll
            for (int i = 0; i < 4; ++i) {
                #pragma unroll
                for (int ct = 0; ct < 4; ++ct) tv[i][ct] = qv[i][ct] + acc[ct][i] + bfv[ct];
                float p1 = tv[i][0] + tv[i][1] + tv[i][2] + tv[i][3];
                float p2 = tv[i][0]*tv[i][0] + tv[i][1]*tv[i][1] + tv[i][2]*tv[i][2] + tv[i][3]*tv[i][3];
                #pragma unroll
                for (int o = 1; o < 16; o <<= 1) { p1 += __shfl_xor(p1, o, 64); p2 += __shfl_xor(p2, o, 64); }
                if (l16 == 0) st2[(q4 * 4 + i) * 4 + wave] = make_float2(p1, p2);
            }
        }

        // write staged next A-tile into alternate buffer (last read 2 barriers ago)
        if (s < 4) {
            #pragma unroll
            for (int it = 0; it < 4; ++it) {
                int c = tid + it * 256;
                float4 v = nreg[it];
                uint2 p;
                p.x = (unsigned int)f2b(v.x) | ((unsigned int)f2b(v.y) << 16);
                p.y = (unsigned int)f2b(v.z) | ((unsigned int)f2b(v.w) << 16);
                *(uint2*)(&Ab[cur ^ 1][(c >> 6) * ASTR + ((c & 63) << 2)]) = p;
            }
        }
        __syncthreads();  // B1: stats visible; next A-tile written

        // combine: comb += g_s * (s==0 ? t : LN(t))
        if (s == 0) {
            #pragma unroll
            for (int i = 0; i < 4; ++i)
                #pragma unroll
                for (int ct = 0; ct < 4; ++ct) comb[i][ct] += gsv[i] * tv[i][ct];
        } else {
            #pragma unroll
            for (int i = 0; i < 4; ++i) {
                float s1 = 0.f, s2 = 0.f;
                #pragma unroll
                for (int w2 = 0; w2 < 4; ++w2) { float2 v = st2[(q4 * 4 + i) * 4 + w2]; s1 += v.x; s2 += v.y; }
                float mn = s1 * (1.f / 256.f);
                float vr = s2 * (1.f / 256.f) - mn * mn;
                float rs = rsqrtf(vr + 1e-5f);
                #pragma unroll
                for (int ct = 0; ct < 4; ++ct)
                    comb[i][ct] += gsv[i] * ((tv[i][ct] - mn) * rs * cgv[ct] + cbv[ct]);
            }
        }
        __syncthreads();  // B2: st2 free for next s; buffer swap safe
        cur ^= 1;
    }

    // ---- final LN and store ----
    float fgv[4], fbv[4];
    #pragma unroll
    for (int ct = 0; ct < 4; ++ct) {
        fgv[ct] = fln_g[colb + ct * 16 + l16];
        fbv[ct] = fln_b[colb + ct * 16 + l16];
    }
    float tf[4][4];
    #pragma unroll
    for (int i = 0; i < 4; ++i) {
        #pragma unroll
        for (int ct = 0; ct < 4; ++ct) tf[i][ct] = qv[i][ct] + comb[i][ct];
        float p1 = tf[i][0] + tf[i][1] + tf[i][2] + tf[i][3];
        float p2 = tf[i][0]*tf[i][0] + tf[i][1]*tf[i][1] + tf[i][2]*tf[i][2] + tf[i][3]*tf[i][3];
        #pragma unroll
        for (int o = 1; o < 16; o <<= 1) { p1 += __shfl_xor(p1, o, 64); p2 += __shfl_xor(p2, o, 64); }
        if (l16 == 0) st2[(q4 * 4 + i) * 4 + wave] = make_float2(p1, p2);
    }
    __syncthreads();
    #pragma unroll
    for (int i = 0; i < 4; ++i) {
        float s1 = 0.f, s2 = 0.f;
        #pragma unroll
        for (int w2 = 0; w2 < 4; ++w2) { float2 v = st2[(q4 * 4 + i) * 4 + w2]; s1 += v.x; s2 += v.y; }
        float mn = s1 * (1.f / 256.f);
        float vr = s2 * (1.f / 256.f) - mn * mn;
        float rs = rsqrtf(vr + 1e-5f);
        #pragma unroll
        for (int ct = 0; ct < 4; ++ct)
            out[(size_t)(b0 + q4 * 4 + i) * 256 + colb + ct * 16 + l16] =
                (tf[i][ct] - mn) * rs * fgv[ct] + fbv[ct];
    }
}

extern "C" void kernel_launch(void* const* d_in, const int* in_sizes, int n_in,
                              void* d_out, int out_size, void* d_ws, size_t ws_size,
                              hipStream_t stream) {
    const float* x    = (const float*)d_in[0];
    const float* sWi  = (const float*)d_in[1];
    const float* sbi  = (const float*)d_in[2];
    const float* sWo  = (const float*)d_in[3];
    const float* sbo  = (const float*)d_in[4];
    const float* cWi  = (const float*)d_in[5];
    const float* cbi  = (const float*)d_in[6];
    const float* cWo  = (const float*)d_in[7];
    const float* cbo  = (const float*)d_in[8];
    const float* clng = (const float*)d_in[9];
    const float* clnb = (const float*)d_in[10];
    const float* glng = (const float*)d_in[11];
    const float* glnb = (const float*)d_in[12];
    const float* gW   = (const float*)d_in[13];
    const float* gb   = (const float*)d_in[14];
    const float* flng = (const float*)d_in[15];
    const float* flnb = (const float*)d_in[16];
    const int* midx   = (const int*)d_in[17];
    float* out        = (float*)d_out;

    char* ws = (char*)d_ws;
    unsigned short* WF = (unsigned short*)ws;         // 5*256*256*2 = 655360 B
    float* BF          = (float*)(ws + 655360);       // 5*256*4 = 5120 B  (total 660480 B)

    k_fuse<<<dim3(64, 5), 256, 0, stream>>>(sWi, sbi, sWo, sbo, cWi, cbi, cWo, cbo, WF, BF);
    k_main<<<1024, 256, 0, stream>>>(x, WF, BF, clng, clnb, glng, glnb, gW, gb, flng, flnb, midx, out);
}

// Round 3
// 284.727 us; speedup vs baseline: 1.0311x; 1.0311x over previous
//
#include <hip/hip_runtime.h>

// GatedCrossModalAttention: B=16384, NM=5, D=256, H=8. FP32 I/O, bf16 internal.
// Attention collapses (Lq=Lk=1 => softmax==1):
//   branch_s(x) = x[:,mod_s] @ (Wo_s@Wv_s)^T + (Wo_s@bv_s+bo_s).
// K1: fuse weights -> WF bf16 [5][256][256] ([out][in]), BF f32 [5][256]  (660 KB ws ONLY)
// Round-2 lesson: 43 MB Y workspace overflowed ws_size -> corrupted inputs. ws stays tiny.
// Round-3 lesson: widening blocks (8 waves) raised occupancy 21->41% but only -8%:
//   limiter is the per-block serial phase chain count per CU, not wave count.
// Round-4 lesson: MFMA-layout epilogue (scalar scattered q loads + out stores)
//   amplified traffic (FETCH 44->128 MB, WRITE 16->77 MB) -> 2x SLOWER. The Yb bf16
//   LDS park is the layout converter that keeps global I/O float4-coalesced. KEEP IT.
// Round-5 (this): Round-1 structure (coalesced, Yb park, full-wave wred) at
//   16 rows / 256 thr / grid 1024, LDS 17.4 KB (gWs dropped, A/Yb halved) ->
//   ~6 blocks/CU = 6 independent chains to overlap stage->GEMM->epilogue latency.

typedef __attribute__((ext_vector_type(8))) short short8;
typedef __attribute__((ext_vector_type(4))) float floatx4;

__device__ __forceinline__ float b2f(unsigned short h) {
    union { unsigned int u; float f; } v; v.u = ((unsigned int)h) << 16; return v.f;
}
__device__ __forceinline__ unsigned short f2b(float f) {
    union { unsigned int u; float f; } v; v.f = f;
    unsigned int u = v.u;
    return (unsigned short)((u + 0x7FFFu + ((u >> 16) & 1u)) >> 16);
}

// ---------------- K1: weight fusion ----------------
// grid (64, 5), block 256. Each block: 4 output rows of one branch.
__global__ __launch_bounds__(256) void k_fuse(
    const float* __restrict__ sWi, const float* __restrict__ sbi,
    const float* __restrict__ sWo, const float* __restrict__ sbo,
    const float* __restrict__ cWi, const float* __restrict__ cbi,
    const float* __restrict__ cWo, const float* __restrict__ cbo,
    unsigned short* __restrict__ WF, float* __restrict__ BF)
{
    int s = blockIdx.y;
    int i0 = blockIdx.x * 4;
    int tid = threadIdx.x;
    const float *Wo, *Wv, *bv, *bo;
    if (s == 0) { Wo = sWo; Wv = sWi + 512 * 256; bv = sbi + 512; bo = sbo; }
    else {
        int n = s - 1;
        Wo = cWo + n * 65536;
        Wv = cWi + n * 768 * 256 + 512 * 256;
        bv = cbi + n * 768 + 512;
        bo = cbo + n * 256;
    }
    __shared__ float wo[4 * 256];
    #pragma unroll
    for (int it = 0; it < 4; ++it) {
        int idx = tid + it * 256;
        wo[idx] = Wo[i0 * 256 + idx];
    }
    __syncthreads();
    float a0 = 0.f, a1 = 0.f, a2 = 0.f, a3 = 0.f;
    #pragma unroll 8
    for (int k = 0; k < 256; ++k) {
        float wv = Wv[k * 256 + tid];
        a0 += wo[k] * wv;
        a1 += wo[256 + k] * wv;
        a2 += wo[512 + k] * wv;
        a3 += wo[768 + k] * wv;
    }
    unsigned short* dst = WF + ((size_t)s * 256 + i0) * 256 + tid;
    dst[0] = f2b(a0); dst[256] = f2b(a1); dst[512] = f2b(a2); dst[768] = f2b(a3);
    // bias: one wave per output row, lane l covers k=4l..4l+3
    int wv_ = tid >> 6, ln = tid & 63;
    float p = 0.f;
    #pragma unroll
    for (int u = 0; u < 4; ++u) {
        int k = ln * 4 + u;
        p += wo[wv_ * 256 + k] * bv[k];
    }
    #pragma unroll
    for (int o = 32; o > 0; o >>= 1) p += __shfl_xor(p, o, 64);
    if (ln == 0) BF[s * 256 + i0 + wv_] = p + bo[i0 + wv_];
}

// ---------------- K2: fused GEMM + epilogue ----------------
__device__ __forceinline__ float wred(float v) {
    #pragma unroll
    for (int o = 32; o > 0; o >>= 1) v += __shfl_xor(v, o, 64);
    return v;
}

// grid 1024, block 256 (4 waves). Block: rows [b0, b0+16). Wave w: GEMM cols
// [w*64, w*64+64) (ct=0..3), epilogue rows [w*4, w*4+4) with lane j = lane*4.
__global__ __launch_bounds__(256, 6) void k_main(
    const float* __restrict__ x, const unsigned short* __restrict__ WF,
    const float* __restrict__ BF,
    const float* __restrict__ cln_g, const float* __restrict__ cln_b,
    const float* __restrict__ gln_g, const float* __restrict__ gln_b,
    const float* __restrict__ gW, const float* __restrict__ gb,
    const float* __restrict__ fln_g, const float* __restrict__ fln_b,
    const int* __restrict__ midx, float* __restrict__ out)
{
    __shared__ __align__(16) unsigned short A[16 * 264];   // branch A-tile, bf16
    __shared__ __align__(16) unsigned short Yb[16 * 264];  // branch result, bf16
    __shared__ float gLDS[16 * 8];                          // gates per row

    const int m = midx[0];
    const int b0 = blockIdx.x * 16;
    const int tid = threadIdx.x;
    const int wave = tid >> 6, lane = tid & 63;
    const int l16 = lane & 15, q4 = lane >> 4;
    const int j = lane * 4;

    // load q rows (fp32, kept in registers for residuals): 4 rows per wave
    float qv[4][4];
    #pragma unroll
    for (int rr = 0; rr < 4; ++rr) {
        int r = wave * 4 + rr;
        float4 u = *(const float4*)(x + ((size_t)(b0 + r) * 5 + m) * 256 + j);
        qv[rr][0] = u.x; qv[rr][1] = u.y; qv[rr][2] = u.z; qv[rr][3] = u.w;
    }
    float4 glg = *(const float4*)(gln_g + j);
    float4 glb = *(const float4*)(gln_b + j);
    float gbv[5];
    #pragma unroll
    for (int n = 0; n < 5; ++n) gbv[n] = gb[n];

    // gates per row (gW read straight from global; L2-resident, coalesced float4)
    #pragma unroll
    for (int rr = 0; rr < 4; ++rr) {
        int r = wave * 4 + rr;
        float s1 = wred(qv[rr][0] + qv[rr][1] + qv[rr][2] + qv[rr][3]);
        float s2 = wred(qv[rr][0]*qv[rr][0] + qv[rr][1]*qv[rr][1] +
                        qv[rr][2]*qv[rr][2] + qv[rr][3]*qv[rr][3]);
        float mn = s1 * (1.f / 256.f);
        float vr = s2 * (1.f / 256.f) - mn * mn;
        float rs = rsqrtf(vr + 1e-5f);
        float qln[4];
        qln[0] = (qv[rr][0] - mn) * rs * glg.x + glb.x;
        qln[1] = (qv[rr][1] - mn) * rs * glg.y + glb.y;
        qln[2] = (qv[rr][2] - mn) * rs * glg.z + glb.z;
        qln[3] = (qv[rr][3] - mn) * rs * glg.w + glb.w;
        float g[5];
        #pragma unroll
        for (int n = 0; n < 5; ++n) {
            float4 w4 = *(const float4*)(gW + n * 256 + j);
            float p = qln[0] * w4.x + qln[1] * w4.y + qln[2] * w4.z + qln[3] * w4.w;
            g[n] = wred(p) + gbv[n];
        }
        float mx = g[0];
        #pragma unroll
        for (int n = 1; n < 5; ++n) mx = fmaxf(mx, g[n]);
        float es = 0.f;
        #pragma unroll
        for (int n = 0; n < 5; ++n) { g[n] = __expf(g[n] - mx); es += g[n]; }
        float inv = 1.f / es;
        if (lane == 0) {
            #pragma unroll
            for (int n = 0; n < 5; ++n) gLDS[r * 8 + n] = g[n] * inv;
        }
    }

    float comb[4][4];
    #pragma unroll
    for (int rr = 0; rr < 4; ++rr)
        #pragma unroll
        for (int i = 0; i < 4; ++i) comb[rr][i] = 0.f;

    for (int s = 0; s < 5; ++s) {
        int mod = (s == 0) ? m : ((s - 1 < m) ? s - 1 : s);
        // stage A: 16 rows x 256 cols of x[:, mod, :], fp32 -> bf16 (1024 float4 / 256 thr)
        #pragma unroll
        for (int it = 0; it < 4; ++it) {
            int c = tid + it * 256;
            int row = c >> 6;
            int c4 = (c & 63) << 2;
            float4 v = *(const float4*)(x + ((size_t)(b0 + row) * 5 + mod) * 256 + c4);
            uint2 p;
            p.x = (unsigned int)f2b(v.x) | ((unsigned int)f2b(v.y) << 16);
            p.y = (unsigned int)f2b(v.z) | ((unsigned int)f2b(v.w) << 16);
            *(uint2*)(&A[row * 264 + c4]) = p;
        }
        __syncthreads();  // B1: A ready (also orders prev-s Yb reads before new park)

        // GEMM: 16x256 = A(16x256) * WF_s^T ; wave covers 64 cols
        floatx4 acc[4];
        #pragma unroll
        for (int ct = 0; ct < 4; ++ct) acc[ct] = (floatx4){0.f, 0.f, 0.f, 0.f};
        const unsigned short* wB = WF + (size_t)s * 65536;
        #pragma unroll
        for (int kk = 0; kk < 8; ++kk) {
            int k = kk * 32 + q4 * 8;
            short8 a = *(const short8*)(&A[l16 * 264 + k]);
            #pragma unroll
            for (int ct = 0; ct < 4; ++ct) {
                short8 bb = *(const short8*)(wB + (size_t)(wave * 64 + ct * 16 + l16) * 256 + k);
                acc[ct] = __builtin_amdgcn_mfma_f32_16x16x32_bf16(a, bb, acc[ct], 0, 0, 0);
            }
        }
        // park result in LDS (bf16) — layout converter: MFMA C-layout -> row-major
        #pragma unroll
        for (int i = 0; i < 4; ++i) {
            int r = q4 * 4 + i;
            #pragma unroll
            for (int ct = 0; ct < 4; ++ct)
                Yb[r * 264 + wave * 64 + ct * 16 + l16] = f2b(acc[ct][i]);
        }
        __syncthreads();  // B2: Yb ready (also: A reads done before next-s staging)

        // epilogue partial: comb += g_s * (s==0 ? y : LN(q+y))
        float4 bfv = *(const float4*)(BF + s * 256 + j);
        if (s == 0) {
            #pragma unroll
            for (int rr = 0; rr < 4; ++rr) {
                int r = wave * 4 + rr;
                uint2 u = *(const uint2*)(&Yb[r * 264 + j]);
                float y0 = b2f(u.x & 0xffff) + bfv.x, y1 = b2f(u.x >> 16) + bfv.y;
                float y2 = b2f(u.y & 0xffff) + bfv.z, y3 = b2f(u.y >> 16) + bfv.w;
                float g0 = gLDS[r * 8 + 0];
                comb[rr][0] += g0 * y0; comb[rr][1] += g0 * y1;
                comb[rr][2] += g0 * y2; comb[rr][3] += g0 * y3;
            }
        } else {
            float4 cg = *(const float4*)(cln_g + (s - 1) * 256 + j);
            float4 cb = *(const float4*)(cln_b + (s - 1) * 256 + j);
            #pragma unroll
            for (int rr = 0; rr < 4; ++rr) {
                int r = wave * 4 + rr;
                uint2 u = *(const uint2*)(&Yb[r * 264 + j]);
                float t0 = qv[rr][0] + b2f(u.x & 0xffff) + bfv.x;
                float t1 = qv[rr][1] + b2f(u.x >> 16)    + bfv.y;
                float t2 = qv[rr][2] + b2f(u.y & 0xffff) + bfv.z;
                float t3 = qv[rr][3] + b2f(u.y >> 16)    + bfv.w;
                float s1 = wred(t0 + t1 + t2 + t3);
                float s2 = wred(t0*t0 + t1*t1 + t2*t2 + t3*t3);
                float mn = s1 * (1.f / 256.f);
                float vr = s2 * (1.f / 256.f) - mn * mn;
                float rs = rsqrtf(vr + 1e-5f);
                float gs = gLDS[r * 8 + s];
                comb[rr][0] += gs * ((t0 - mn) * rs * cg.x + cb.x);
                comb[rr][1] += gs * ((t1 - mn) * rs * cg.y + cb.y);
                comb[rr][2] += gs * ((t2 - mn) * rs * cg.z + cb.z);
                comb[rr][3] += gs * ((t3 - mn) * rs * cg.w + cb.w);
            }
        }
    }

    // final LN and store (float4-coalesced)
    float4 fg = *(const float4*)(fln_g + j);
    float4 fb = *(const float4*)(fln_b + j);
    #pragma unroll
    for (int rr = 0; rr < 4; ++rr) {
        int r = wave * 4 + rr;
        float t0 = qv[rr][0] + comb[rr][0], t1 = qv[rr][1] + comb[rr][1];
        float t2 = qv[rr][2] + comb[rr][2], t3 = qv[rr][3] + comb[rr][3];
        float s1 = wred(t0 + t1 + t2 + t3);
        float s2 = wred(t0*t0 + t1*t1 + t2*t2 + t3*t3);
        float mn = s1 * (1.f / 256.f);
        float vr = s2 * (1.f / 256.f) - mn * mn;
        float rs = rsqrtf(vr + 1e-5f);
        float4 ov;
        ov.x = (t0 - mn) * rs * fg.x + fb.x;
        ov.y = (t1 - mn) * rs * fg.y + fb.y;
        ov.z = (t2 - mn) * rs * fg.z + fb.z;
        ov.w = (t3 - mn) * rs * fg.w + fb.w;
        *(float4*)(out + (size_t)(b0 + r) * 256 + j) = ov;
    }
}

extern "C" void kernel_launch(void* const* d_in, const int* in_sizes, int n_in,
                              void* d_out, int out_size, void* d_ws, size_t ws_size,
                              hipStream_t stream) {
    const float* x    = (const float*)d_in[0];
    const float* sWi  = (const float*)d_in[1];
    const float* sbi  = (const float*)d_in[2];
    const float* sWo  = (const float*)d_in[3];
    const float* sbo  = (const float*)d_in[4];
    const float* cWi  = (const float*)d_in[5];
    const float* cbi  = (const float*)d_in[6];
    const float* cWo  = (const float*)d_in[7];
    const float* cbo  = (const float*)d_in[8];
    const float* clng = (const float*)d_in[9];
    const float* clnb = (const float*)d_in[10];
    const float* glng = (const float*)d_in[11];
    const float* glnb = (const float*)d_in[12];
    const float* gW   = (const float*)d_in[13];
    const float* gb   = (const float*)d_in[14];
    const float* flng = (const float*)d_in[15];
    const float* flnb = (const float*)d_in[16];
    const int* midx   = (const int*)d_in[17];
    float* out        = (float*)d_out;

    char* ws = (char*)d_ws;
    unsigned short* WF = (unsigned short*)ws;         // 5*256*256*2 = 655360 B
    float* BF          = (float*)(ws + 655360);       // 5*256*4 = 5120 B  (total 660480 B)

    k_fuse<<<dim3(64, 5), 256, 0, stream>>>(sWi, sbi, sWo, sbo, cWi, cbi, cWo, cbo, WF, BF);
    k_main<<<1024, 256, 0, stream>>>(x, WF, BF, clng, clnb, glng, glnb, gW, gb, flng, flnb, midx, out);
}

// Round 4
// 228.622 us; speedup vs baseline: 1.2841x; 1.2454x over previous
//
#include <hip/hip_runtime.h>

// GatedCrossModalAttention: B=16384, NM=5, D=256, H=8. FP32 I/O, bf16 internal.
// Attention collapses (Lq=Lk=1 => softmax==1):
//   branch_s(x) = x[:,mod_s] @ (Wo_s@Wv_s)^T + (Wo_s@bv_s+bo_s).
// K1: fuse weights -> WF bf16 [5][256][256] ([out][in]), BF f32 [5][256]  (660 KB ws ONLY)
// Round-2 lesson: 43 MB Y workspace overflowed ws_size -> corrupted inputs. ws stays tiny.
// Round-3 lesson: occupancy alone (8 waves vs 4, same grid) bought only -8%:
//   limiter is the serial phase chain, ~2 chains/CU.
// Round-4 lesson: MFMA-layout epilogue (scattered scalar q/out access) amplified
//   traffic (FETCH 44->128, WRITE 16->77 MB) -> 2x slower. Yb LDS park IS the
//   layout converter that keeps global I/O float4-coalesced. KEEP IT.
// Round-5 lesson: 1024 x 16-row blocks ALSO inflate traffic (109/57 MB) even with
//   the park restored -> structure-dependent cache thrash. 512 x 32-row is the
//   known-good regime (FETCH/WRITE signature 43.7/16.4 MB).
// Round-6 (this): R1 structure verbatim + T14 async-stage split ONLY:
//   issue next-branch A loads into regs BEFORE the GEMM, ds-write into a
//   double-buffered A after the GEMM -> stage latency hides under MFMA instead of
//   sitting naked between barriers. Same barrier count. LDS 57 KB (free: grid
//   caps residency at 2 blocks/CU). k_fuse reverted to R1-exact (absmax 0.015625).

typedef __attribute__((ext_vector_type(8))) short short8;
typedef __attribute__((ext_vector_type(4))) float floatx4;

__device__ __forceinline__ float b2f(unsigned short h) {
    union { unsigned int u; float f; } v; v.u = ((unsigned int)h) << 16; return v.f;
}
__device__ __forceinline__ unsigned short f2b(float f) {
    union { unsigned int u; float f; } v; v.f = f;
    unsigned int u = v.u;
    return (unsigned short)((u + 0x7FFFu + ((u >> 16) & 1u)) >> 16);
}

// ---------------- K1: weight fusion ----------------
// grid (64, 5), block 256. Each block: 4 output rows of one branch.
__global__ __launch_bounds__(256) void k_fuse(
    const float* __restrict__ sWi, const float* __restrict__ sbi,
    const float* __restrict__ sWo, const float* __restrict__ sbo,
    const float* __restrict__ cWi, const float* __restrict__ cbi,
    const float* __restrict__ cWo, const float* __restrict__ cbo,
    unsigned short* __restrict__ WF, float* __restrict__ BF)
{
    int s = blockIdx.y;
    int i0 = blockIdx.x * 4;
    int tid = threadIdx.x;
    const float *Wo, *Wv, *bv, *bo;
    if (s == 0) { Wo = sWo; Wv = sWi + 512 * 256; bv = sbi + 512; bo = sbo; }
    else {
        int n = s - 1;
        Wo = cWo + n * 65536;
        Wv = cWi + n * 768 * 256 + 512 * 256;
        bv = cbi + n * 768 + 512;
        bo = cbo + n * 256;
    }
    __shared__ float wo[4 * 256];
    #pragma unroll
    for (int it = 0; it < 4; ++it) {
        int idx = tid + it * 256;
        wo[idx] = Wo[i0 * 256 + idx];
    }
    __syncthreads();
    float a0 = 0.f, a1 = 0.f, a2 = 0.f, a3 = 0.f;
    for (int k = 0; k < 256; ++k) {
        float wv = Wv[k * 256 + tid];
        a0 += wo[k] * wv;
        a1 += wo[256 + k] * wv;
        a2 += wo[512 + k] * wv;
        a3 += wo[768 + k] * wv;
    }
    unsigned short* dst = WF + ((size_t)s * 256 + i0) * 256 + tid;
    dst[0] = f2b(a0); dst[256] = f2b(a1); dst[512] = f2b(a2); dst[768] = f2b(a3);
    if (tid < 4) {
        int i = i0 + tid;
        float bacc = 0.f;
        for (int k = 0; k < 256; ++k) bacc += Wo[i * 256 + k] * bv[k];
        BF[s * 256 + i] = bacc + bo[i];
    }
}

// ---------------- K2: fused GEMM + epilogue ----------------
__device__ __forceinline__ float wred(float v) {
    #pragma unroll
    for (int o = 32; o > 0; o >>= 1) v += __shfl_xor(v, o, 64);
    return v;
}

// grid 512, block 512 (8 waves). Block: rows [b0, b0+32). Wave w: GEMM cols
// [w*32, w*32+32), epilogue rows [w*4, w*4+4) (lane j = lane*4 .. +3).
__global__ __launch_bounds__(512, 4) void k_main(
    const float* __restrict__ x, const unsigned short* __restrict__ WF,
    const float* __restrict__ BF,
    const float* __restrict__ cln_g, const float* __restrict__ cln_b,
    const float* __restrict__ gln_g, const float* __restrict__ gln_b,
    const float* __restrict__ gW, const float* __restrict__ gb,
    const float* __restrict__ fln_g, const float* __restrict__ fln_b,
    const int* __restrict__ midx, float* __restrict__ out)
{
    __shared__ __align__(16) unsigned short Ab[2][32 * 264]; // double-buffered A-tile, bf16
    __shared__ __align__(16) unsigned short Yb[32 * 264];    // branch result, bf16
    __shared__ float gWs[5 * 256];
    __shared__ float gLDS[32 * 8];                            // gates per row

    int m = midx[0];
    int b0 = blockIdx.x * 32;
    int tid = threadIdx.x;
    int wave = tid >> 6, lane = tid & 63;
    int l16 = lane & 15, q4 = lane >> 4;
    int j = lane * 4;

    // stage gate weights (1280 floats, 512 threads)
    gWs[tid] = gW[tid];
    gWs[tid + 512] = gW[tid + 512];
    if (tid < 256) gWs[tid + 1024] = gW[tid + 1024];

    // stage s=0 A-tile (branch 0 reads modal m) straight into buf0
    {
        #pragma unroll
        for (int it = 0; it < 4; ++it) {
            int c = tid + it * 512;
            int row = c >> 6;
            int c4 = (c & 63) << 2;
            float4 v = *(const float4*)(x + ((size_t)(b0 + row) * 5 + m) * 256 + c4);
            uint2 p;
            p.x = (unsigned int)f2b(v.x) | ((unsigned int)f2b(v.y) << 16);
            p.y = (unsigned int)f2b(v.z) | ((unsigned int)f2b(v.w) << 16);
            *(uint2*)(&Ab[0][row * 264 + c4]) = p;
        }
    }

    // load q rows (fp32, kept in registers for residuals): 4 rows per wave
    float qv[4][4];
    #pragma unroll
    for (int rr = 0; rr < 4; ++rr) {
        int r = wave * 4 + rr;
        float4 u = *(const float4*)(x + ((size_t)(b0 + r) * 5 + m) * 256 + j);
        qv[rr][0] = u.x; qv[rr][1] = u.y; qv[rr][2] = u.z; qv[rr][3] = u.w;
    }
    float4 glg = *(const float4*)(gln_g + j);
    float4 glb = *(const float4*)(gln_b + j);
    float gbv[5];
    #pragma unroll
    for (int n = 0; n < 5; ++n) gbv[n] = gb[n];

    __syncthreads();  // gWs + A buf0 ready

    // gates per row
    #pragma unroll
    for (int rr = 0; rr < 4; ++rr) {
        int r = wave * 4 + rr;
        float s1 = wred(qv[rr][0] + qv[rr][1] + qv[rr][2] + qv[rr][3]);
        float s2 = wred(qv[rr][0]*qv[rr][0] + qv[rr][1]*qv[rr][1] +
                        qv[rr][2]*qv[rr][2] + qv[rr][3]*qv[rr][3]);
        float mn = s1 * (1.f / 256.f);
        float vr = s2 * (1.f / 256.f) - mn * mn;
        float rs = rsqrtf(vr + 1e-5f);
        float qln[4];
        qln[0] = (qv[rr][0] - mn) * rs * glg.x + glb.x;
        qln[1] = (qv[rr][1] - mn) * rs * glg.y + glb.y;
        qln[2] = (qv[rr][2] - mn) * rs * glg.z + glb.z;
        qln[3] = (qv[rr][3] - mn) * rs * glg.w + glb.w;
        float g[5];
        #pragma unroll
        for (int n = 0; n < 5; ++n) {
            float p = qln[0] * gWs[n * 256 + j] + qln[1] * gWs[n * 256 + j + 1]
                    + qln[2] * gWs[n * 256 + j + 2] + qln[3] * gWs[n * 256 + j + 3];
            g[n] = wred(p) + gbv[n];
        }
        float mx = g[0];
        #pragma unroll
        for (int n = 1; n < 5; ++n) mx = fmaxf(mx, g[n]);
        float es = 0.f;
        #pragma unroll
        for (int n = 0; n < 5; ++n) { g[n] = __expf(g[n] - mx); es += g[n]; }
        float inv = 1.f / es;
        if (lane == 0) {
            #pragma unroll
            for (int n = 0; n < 5; ++n) gLDS[r * 8 + n] = g[n] * inv;
        }
    }
    // gLDS consumed after B1 of s=0 (barrier below orders it)

    float comb[4][4];
    #pragma unroll
    for (int rr = 0; rr < 4; ++rr)
        #pragma unroll
        for (int i = 0; i < 4; ++i) comb[rr][i] = 0.f;

    int cur = 0;
    for (int s = 0; s < 5; ++s) {
        // T14: issue next-branch stage loads NOW (latency hides under GEMM)
        float4 nreg[4];
        if (s < 4) {
            int nmod = (s < m) ? s : s + 1;   // modal of branch s+1
            #pragma unroll
            for (int it = 0; it < 4; ++it) {
                int c = tid + it * 512;
                nreg[it] = *(const float4*)(x + ((size_t)(b0 + (c >> 6)) * 5 + nmod) * 256 + ((c & 63) << 2));
            }
        }
        // prefetch per-s epilogue params (off the B1->epilogue path)
        float4 bfv = *(const float4*)(BF + s * 256 + j);
        float4 cg, cb;
        if (s > 0) {
            cg = *(const float4*)(cln_g + (s - 1) * 256 + j);
            cb = *(const float4*)(cln_b + (s - 1) * 256 + j);
        }

        // GEMM: 32x256 += A(32x256) * WF_s^T ; wave covers 32 cols
        floatx4 acc[2][2];
        #pragma unroll
        for (int rt = 0; rt < 2; ++rt)
            #pragma unroll
            for (int ct = 0; ct < 2; ++ct) acc[rt][ct] = (floatx4){0.f, 0.f, 0.f, 0.f};
        const unsigned short* wB = WF + (size_t)s * 65536;
        #pragma unroll
        for (int kk = 0; kk < 8; ++kk) {
            int k = kk * 32 + q4 * 8;
            short8 a0 = *(const short8*)(&Ab[cur][l16 * 264 + k]);
            short8 a1 = *(const short8*)(&Ab[cur][(16 + l16) * 264 + k]);
            short8 bb[2];
            #pragma unroll
            for (int ct = 0; ct < 2; ++ct)
                bb[ct] = *(const short8*)(wB + (size_t)(wave * 32 + ct * 16 + l16) * 256 + k);
            #pragma unroll
            for (int ct = 0; ct < 2; ++ct) {
                acc[0][ct] = __builtin_amdgcn_mfma_f32_16x16x32_bf16(a0, bb[ct], acc[0][ct], 0, 0, 0);
                acc[1][ct] = __builtin_amdgcn_mfma_f32_16x16x32_bf16(a1, bb[ct], acc[1][ct], 0, 0, 0);
            }
        }
        // park result in LDS (bf16) — layout converter: MFMA C-layout -> row-major
        #pragma unroll
        for (int rt = 0; rt < 2; ++rt)
            #pragma unroll
            for (int i = 0; i < 4; ++i) {
                int r = rt * 16 + q4 * 4 + i;
                #pragma unroll
                for (int ct = 0; ct < 2; ++ct)
                    Yb[r * 264 + wave * 32 + ct * 16 + l16] = f2b(acc[rt][ct][i]);
            }
        // write staged next A-tile into the alternate buffer (loads long in flight)
        if (s < 4) {
            #pragma unroll
            for (int it = 0; it < 4; ++it) {
                int c = tid + it * 512;
                float4 v = nreg[it];
                uint2 p;
                p.x = (unsigned int)f2b(v.x) | ((unsigned int)f2b(v.y) << 16);
                p.y = (unsigned int)f2b(v.z) | ((unsigned int)f2b(v.w) << 16);
                *(uint2*)(&Ab[cur ^ 1][(c >> 6) * 264 + ((c & 63) << 2)]) = p;
            }
        }
        __syncthreads();  // B1: Yb + next A-tile ready (also orders gLDS at s=0)

        // epilogue partial: comb += g_s * (s==0 ? y : LN(q+y))
        if (s == 0) {
            #pragma unroll
            for (int rr = 0; rr < 4; ++rr) {
                int r = wave * 4 + rr;
                uint2 u = *(const uint2*)(&Yb[r * 264 + j]);
                float y0 = b2f(u.x & 0xffff) + bfv.x, y1 = b2f(u.x >> 16) + bfv.y;
                float y2 = b2f(u.y & 0xffff) + bfv.z, y3 = b2f(u.y >> 16) + bfv.w;
                float g0 = gLDS[r * 8 + 0];
                comb[rr][0] += g0 * y0; comb[rr][1] += g0 * y1;
                comb[rr][2] += g0 * y2; comb[rr][3] += g0 * y3;
            }
        } else {
            #pragma unroll
            for (int rr = 0; rr < 4; ++rr) {
                int r = wave * 4 + rr;
                uint2 u = *(const uint2*)(&Yb[r * 264 + j]);
                float t0 = qv[rr][0] + b2f(u.x & 0xffff) + bfv.x;
                float t1 = qv[rr][1] + b2f(u.x >> 16)    + bfv.y;
                float t2 = qv[rr][2] + b2f(u.y & 0xffff) + bfv.z;
                float t3 = qv[rr][3] + b2f(u.y >> 16)    + bfv.w;
                float s1 = wred(t0 + t1 + t2 + t3);
                float s2 = wred(t0*t0 + t1*t1 + t2*t2 + t3*t3);
                float mn = s1 * (1.f / 256.f);
                float vr = s2 * (1.f / 256.f) - mn * mn;
                float rs = rsqrtf(vr + 1e-5f);
                float gs = gLDS[r * 8 + s];
                comb[rr][0] += gs * ((t0 - mn) * rs * cg.x + cb.x);
                comb[rr][1] += gs * ((t1 - mn) * rs * cg.y + cb.y);
                comb[rr][2] += gs * ((t2 - mn) * rs * cg.z + cb.z);
                comb[rr][3] += gs * ((t3 - mn) * rs * cg.w + cb.w);
            }
        }
        __syncthreads();  // B2: Yb reads done before next park; A[cur] reads done
        cur ^= 1;
    }

    // final LN and store (float4-coalesced)
    float4 fg = *(const float4*)(fln_g + j);
    float4 fb = *(const float4*)(fln_b + j);
    #pragma unroll
    for (int rr = 0; rr < 4; ++rr) {
        int r = wave * 4 + rr;
        float t0 = qv[rr][0] + comb[rr][0], t1 = qv[rr][1] + comb[rr][1];
        float t2 = qv[rr][2] + comb[rr][2], t3 = qv[rr][3] + comb[rr][3];
        float s1 = wred(t0 + t1 + t2 + t3);
        float s2 = wred(t0*t0 + t1*t1 + t2*t2 + t3*t3);
        float mn = s1 * (1.f / 256.f);
        float vr = s2 * (1.f / 256.f) - mn * mn;
        float rs = rsqrtf(vr + 1e-5f);
        float4 ov;
        ov.x = (t0 - mn) * rs * fg.x + fb.x;
        ov.y = (t1 - mn) * rs * fg.y + fb.y;
        ov.z = (t2 - mn) * rs * fg.z + fb.z;
        ov.w = (t3 - mn) * rs * fg.w + fb.w;
        *(float4*)(out + (size_t)(b0 + r) * 256 + j) = ov;
    }
}

extern "C" void kernel_launch(void* const* d_in, const int* in_sizes, int n_in,
                              void* d_out, int out_size, void* d_ws, size_t ws_size,
                              hipStream_t stream) {
    const float* x    = (const float*)d_in[0];
    const float* sWi  = (const float*)d_in[1];
    const float* sbi  = (const float*)d_in[2];
    const float* sWo  = (const float*)d_in[3];
    const float* sbo  = (const float*)d_in[4];
    const float* cWi  = (const float*)d_in[5];
    const float* cbi  = (const float*)d_in[6];
    const float* cWo  = (const float*)d_in[7];
    const float* cbo  = (const float*)d_in[8];
    const float* clng = (const float*)d_in[9];
    const float* clnb = (const float*)d_in[10];
    const float* glng = (const float*)d_in[11];
    const float* glnb = (const float*)d_in[12];
    const float* gW   = (const float*)d_in[13];
    const float* gb   = (const float*)d_in[14];
    const float* flng = (const float*)d_in[15];
    const float* flnb = (const float*)d_in[16];
    const int* midx   = (const int*)d_in[17];
    float* out        = (float*)d_out;

    char* ws = (char*)d_ws;
    unsigned short* WF = (unsigned short*)ws;         // 5*256*256*2 = 655360 B
    float* BF          = (float*)(ws + 655360);       // 5*256*4 = 5120 B  (total 660480 B)

    k_fuse<<<dim3(64, 5), 256, 0, stream>>>(sWi, sbi, sWo, sbo, cWi, cbi, cWo, cbo, WF, BF);
    k_main<<<512, 512, 0, stream>>>(x, WF, BF, clng, clnb, glng, glnb, gW, gb, flng, flnb, midx, out);
}

// Round 5
// 212.784 us; speedup vs baseline: 1.3797x; 1.0744x over previous
//
#include <hip/hip_runtime.h>

// GatedCrossModalAttention: B=16384, NM=5, D=256, H=8. FP32 I/O, bf16 internal.
// Attention collapses (Lq=Lk=1 => softmax==1):
//   branch_s(x) = x[:,mod_s] @ (Wo_s@Wv_s)^T + (Wo_s@bv_s+bo_s).
// K1: fuse weights -> WT bf16 [5][8][8][2][4][16][8] (MFMA-fragment order, see below),
//     BF f32 [5][256]. ws usage 660 KB ONLY (Round-2 lesson: big ws corrupted inputs).
// Round-3 lesson: occupancy alone bought -8%; limiter is the per-block serial chain.
// Round-4 lesson: MFMA-layout epilogue -> scattered global I/O -> 2x traffic -> 2x slower.
//   Yb LDS park IS the layout converter. KEEP IT.
// Round-5 lesson: 1024x16-row blocks inflate traffic (cache thrash). 512x32-row is the
//   known-good regime (FETCH/WRITE signature 43.7/16.4 MB).
// Round-6 lesson: T14 async-stage prefetch = neutral (79.2 vs 78.5) -> stage latency
//   is not the sink. Reverted.
// Round-7 (this): the B-fragment loads were 16-line scatters (16B per lane at 512B
//   lane stride, 256 L2 transactions/wave/iter in front of every MFMA). k_fuse now
//   stores the fused weight pre-swizzled in exact MFMA fragment order:
//     WT[s][kk][wave][ct][q4][l16][e] = WF[wave*32+ct*16+l16][kk*32+q4*8+e]
//   so lane L reads byte offset L*16 -> every bb load is ONE coalesced 1KB wave
//   transaction, issued in two 8-load bursts. Everything else is Round-1-verbatim.

typedef __attribute__((ext_vector_type(8))) short short8;
typedef __attribute__((ext_vector_type(4))) float floatx4;

__device__ __forceinline__ float b2f(unsigned short h) {
    union { unsigned int u; float f; } v; v.u = ((unsigned int)h) << 16; return v.f;
}
__device__ __forceinline__ unsigned short f2b(float f) {
    union { unsigned int u; float f; } v; v.f = f;
    unsigned int u = v.u;
    return (unsigned short)((u + 0x7FFFu + ((u >> 16) & 1u)) >> 16);
}

// ---------------- K1: weight fusion ----------------
// grid (64, 5), block 256. Each block: 4 output rows (n = i0..i0+3) of one branch.
// Thread tid holds k=tid; computes WF[n][k] and scatters into WT fragment order.
__global__ __launch_bounds__(256) void k_fuse(
    const float* __restrict__ sWi, const float* __restrict__ sbi,
    const float* __restrict__ sWo, const float* __restrict__ sbo,
    const float* __restrict__ cWi, const float* __restrict__ cbi,
    const float* __restrict__ cWo, const float* __restrict__ cbo,
    unsigned short* __restrict__ WT, float* __restrict__ BF)
{
    int s = blockIdx.y;
    int i0 = blockIdx.x * 4;
    int tid = threadIdx.x;
    const float *Wo, *Wv, *bv, *bo;
    if (s == 0) { Wo = sWo; Wv = sWi + 512 * 256; bv = sbi + 512; bo = sbo; }
    else {
        int n = s - 1;
        Wo = cWo + n * 65536;
        Wv = cWi + n * 768 * 256 + 512 * 256;
        bv = cbi + n * 768 + 512;
        bo = cbo + n * 256;
    }
    __shared__ float wo[4 * 256];
    #pragma unroll
    for (int it = 0; it < 4; ++it) {
        int idx = tid + it * 256;
        wo[idx] = Wo[i0 * 256 + idx];
    }
    __syncthreads();
    float a0 = 0.f, a1 = 0.f, a2 = 0.f, a3 = 0.f;
    for (int k = 0; k < 256; ++k) {
        float wv = Wv[k * 256 + tid];
        a0 += wo[k] * wv;
        a1 += wo[256 + k] * wv;
        a2 += wo[512 + k] * wv;
        a3 += wo[768 + k] * wv;
    }
    // scatter into WT fragment order:
    // WT[s][kk][w][ct][q4][l16][e]  (kk=k>>5, q4=(k>>3)&3, e=k&7; w=n>>5, ct=(n>>4)&1, l16=n&15)
    {
        unsigned short vals[4] = { f2b(a0), f2b(a1), f2b(a2), f2b(a3) };
        int kk = tid >> 5, q4k = (tid >> 3) & 3, e = tid & 7;
        #pragma unroll
        for (int r = 0; r < 4; ++r) {
            int n = i0 + r;
            int w = n >> 5, ct = (n >> 4) & 1, l16n = n & 15;
            size_t idx = (((((((size_t)s * 8 + kk) * 8 + w) * 2 + ct) * 4 + q4k) * 16 + l16n) * 8) + e;
            WT[idx] = vals[r];
        }
    }
    if (tid < 4) {
        int i = i0 + tid;
        float bacc = 0.f;
        for (int k = 0; k < 256; ++k) bacc += Wo[i * 256 + k] * bv[k];
        BF[s * 256 + i] = bacc + bo[i];
    }
}

// ---------------- K2: fused GEMM + epilogue ----------------
__device__ __forceinline__ float wred(float v) {
    #pragma unroll
    for (int o = 32; o > 0; o >>= 1) v += __shfl_xor(v, o, 64);
    return v;
}

// grid 512, block 512 (8 waves). Block: rows [b0, b0+32). Wave w: GEMM cols
// [w*32, w*32+32), epilogue rows [w*4, w*4+4) (lane j = lane*4 .. +3).
__global__ __launch_bounds__(512, 4) void k_main(
    const float* __restrict__ x, const unsigned short* __restrict__ WT,
    const float* __restrict__ BF,
    const float* __restrict__ cln_g, const float* __restrict__ cln_b,
    const float* __restrict__ gln_g, const float* __restrict__ gln_b,
    const float* __restrict__ gW, const float* __restrict__ gb,
    const float* __restrict__ fln_g, const float* __restrict__ fln_b,
    const int* __restrict__ midx, float* __restrict__ out)
{
    __shared__ __align__(16) unsigned short A[32 * 264];   // branch A-tile, bf16
    __shared__ __align__(16) unsigned short Yb[32 * 264];  // branch result, bf16
    __shared__ float gWs[5 * 256];
    __shared__ float gLDS[32 * 8];                          // gates per row

    int m = midx[0];
    int b0 = blockIdx.x * 32;
    int tid = threadIdx.x;
    int wave = tid >> 6, lane = tid & 63;
    int l16 = lane & 15, q4 = lane >> 4;
    int j = lane * 4;

    // stage gate weights (1280 floats, 512 threads)
    gWs[tid] = gW[tid];
    gWs[tid + 512] = gW[tid + 512];
    if (tid < 256) gWs[tid + 1024] = gW[tid + 1024];

    // load q rows (fp32, kept in registers for residuals): 4 rows per wave
    float qv[4][4];
    #pragma unroll
    for (int rr = 0; rr < 4; ++rr) {
        int r = wave * 4 + rr;
        float4 u = *(const float4*)(x + ((size_t)(b0 + r) * 5 + m) * 256 + j);
        qv[rr][0] = u.x; qv[rr][1] = u.y; qv[rr][2] = u.z; qv[rr][3] = u.w;
    }
    float4 glg = *(const float4*)(gln_g + j);
    float4 glb = *(const float4*)(gln_b + j);
    float gbv[5];
    #pragma unroll
    for (int n = 0; n < 5; ++n) gbv[n] = gb[n];

    __syncthreads();  // gWs ready

    // gates per row
    #pragma unroll
    for (int rr = 0; rr < 4; ++rr) {
        int r = wave * 4 + rr;
        float s1 = wred(qv[rr][0] + qv[rr][1] + qv[rr][2] + qv[rr][3]);
        float s2 = wred(qv[rr][0]*qv[rr][0] + qv[rr][1]*qv[rr][1] +
                        qv[rr][2]*qv[rr][2] + qv[rr][3]*qv[rr][3]);
        float mn = s1 * (1.f / 256.f);
        float vr = s2 * (1.f / 256.f) - mn * mn;
        float rs = rsqrtf(vr + 1e-5f);
        float qln[4];
        qln[0] = (qv[rr][0] - mn) * rs * glg.x + glb.x;
        qln[1] = (qv[rr][1] - mn) * rs * glg.y + glb.y;
        qln[2] = (qv[rr][2] - mn) * rs * glg.z + glb.z;
        qln[3] = (qv[rr][3] - mn) * rs * glg.w + glb.w;
        float g[5];
        #pragma unroll
        for (int n = 0; n < 5; ++n) {
            float p = qln[0] * gWs[n * 256 + j] + qln[1] * gWs[n * 256 + j + 1]
                    + qln[2] * gWs[n * 256 + j + 2] + qln[3] * gWs[n * 256 + j + 3];
            g[n] = wred(p) + gbv[n];
        }
        float mx = g[0];
        #pragma unroll
        for (int n = 1; n < 5; ++n) mx = fmaxf(mx, g[n]);
        float es = 0.f;
        #pragma unroll
        for (int n = 0; n < 5; ++n) { g[n] = __expf(g[n] - mx); es += g[n]; }
        float inv = 1.f / es;
        if (lane == 0) {
            #pragma unroll
            for (int n = 0; n < 5; ++n) gLDS[r * 8 + n] = g[n] * inv;
        }
    }

    float comb[4][4];
    #pragma unroll
    for (int rr = 0; rr < 4; ++rr)
        #pragma unroll
        for (int i = 0; i < 4; ++i) comb[rr][i] = 0.f;

    for (int s = 0; s < 5; ++s) {
        int mod = (s == 0) ? m : ((s - 1 < m) ? s - 1 : s);
        // stage A: 32 rows x 256 cols of x[:, mod, :], fp32 -> bf16 (2048 float4, 512 thr)
        #pragma unroll
        for (int it = 0; it < 4; ++it) {
            int c = tid + it * 512;
            int row = c >> 6;
            int c4 = (c & 63) << 2;
            float4 v = *(const float4*)(x + ((size_t)(b0 + row) * 5 + mod) * 256 + c4);
            uint2 p;
            p.x = (unsigned int)f2b(v.x) | ((unsigned int)f2b(v.y) << 16);
            p.y = (unsigned int)f2b(v.z) | ((unsigned int)f2b(v.w) << 16);
            *(uint2*)(&A[row * 264 + c4]) = p;
        }
        __syncthreads();  // B1: A ready; prev epilogue reads of Yb done before new park

        // GEMM: 32x256 += A(32x256) * WF_s^T ; wave covers 32 cols.
        // B loads from WT: lane L reads byte offset L*16 -> 1KB coalesced per load.
        floatx4 acc[2][2];
        #pragma unroll
        for (int rt = 0; rt < 2; ++rt)
            #pragma unroll
            for (int ct = 0; ct < 2; ++ct) acc[rt][ct] = (floatx4){0.f, 0.f, 0.f, 0.f};
        const unsigned short* wT = WT + (size_t)s * 65536;
        #pragma unroll
        for (int h = 0; h < 2; ++h) {
            short8 bb[8];
            #pragma unroll
            for (int kk = 0; kk < 4; ++kk) {
                int kkg = h * 4 + kk;
                #pragma unroll
                for (int ct = 0; ct < 2; ++ct)
                    bb[kk * 2 + ct] = *(const short8*)(
                        wT + (((((size_t)kkg * 8 + wave) * 2 + ct) * 4 + q4) * 16 + l16) * 8);
            }
            #pragma unroll
            for (int kk = 0; kk < 4; ++kk) {
                int k = (h * 4 + kk) * 32 + q4 * 8;
                short8 a0 = *(const short8*)(&A[l16 * 264 + k]);
                short8 a1 = *(const short8*)(&A[(16 + l16) * 264 + k]);
                acc[0][0] = __builtin_amdgcn_mfma_f32_16x16x32_bf16(a0, bb[kk*2+0], acc[0][0], 0, 0, 0);
                acc[0][1] = __builtin_amdgcn_mfma_f32_16x16x32_bf16(a0, bb[kk*2+1], acc[0][1], 0, 0, 0);
                acc[1][0] = __builtin_amdgcn_mfma_f32_16x16x32_bf16(a1, bb[kk*2+0], acc[1][0], 0, 0, 0);
                acc[1][1] = __builtin_amdgcn_mfma_f32_16x16x32_bf16(a1, bb[kk*2+1], acc[1][1], 0, 0, 0);
            }
        }
        // park result in LDS (bf16) — layout converter: MFMA C-layout -> row-major
        #pragma unroll
        for (int rt = 0; rt < 2; ++rt)
            #pragma unroll
            for (int i = 0; i < 4; ++i) {
                int r = rt * 16 + q4 * 4 + i;
                #pragma unroll
                for (int ct = 0; ct < 2; ++ct)
                    Yb[r * 264 + wave * 32 + ct * 16 + l16] = f2b(acc[rt][ct][i]);
            }
        __syncthreads();  // B2: Yb ready; A reads done before next-s staging

        // epilogue partial: comb += g_s * (s==0 ? y : LN(q+y))
        float4 bfv = *(const float4*)(BF + s * 256 + j);
        if (s == 0) {
            #pragma unroll
            for (int rr = 0; rr < 4; ++rr) {
                int r = wave * 4 + rr;
                uint2 u = *(const uint2*)(&Yb[r * 264 + j]);
                float y0 = b2f(u.x & 0xffff) + bfv.x, y1 = b2f(u.x >> 16) + bfv.y;
                float y2 = b2f(u.y & 0xffff) + bfv.z, y3 = b2f(u.y >> 16) + bfv.w;
                float g0 = gLDS[r * 8 + 0];
                comb[rr][0] += g0 * y0; comb[rr][1] += g0 * y1;
                comb[rr][2] += g0 * y2; comb[rr][3] += g0 * y3;
            }
        } else {
            float4 cg = *(const float4*)(cln_g + (s - 1) * 256 + j);
            float4 cb = *(const float4*)(cln_b + (s - 1) * 256 + j);
            #pragma unroll
            for (int rr = 0; rr < 4; ++rr) {
                int r = wave * 4 + rr;
                uint2 u = *(const uint2*)(&Yb[r * 264 + j]);
                float t0 = qv[rr][0] + b2f(u.x & 0xffff) + bfv.x;
                float t1 = qv[rr][1] + b2f(u.x >> 16)    + bfv.y;
                float t2 = qv[rr][2] + b2f(u.y & 0xffff) + bfv.z;
                float t3 = qv[rr][3] + b2f(u.y >> 16)    + bfv.w;
                float s1 = wred(t0 + t1 + t2 + t3);
                float s2 = wred(t0*t0 + t1*t1 + t2*t2 + t3*t3);
                float mn = s1 * (1.f / 256.f);
                float vr = s2 * (1.f / 256.f) - mn * mn;
                float rs = rsqrtf(vr + 1e-5f);
                float gs = gLDS[r * 8 + s];
                comb[rr][0] += gs * ((t0 - mn) * rs * cg.x + cb.x);
                comb[rr][1] += gs * ((t1 - mn) * rs * cg.y + cb.y);
                comb[rr][2] += gs * ((t2 - mn) * rs * cg.z + cb.z);
                comb[rr][3] += gs * ((t3 - mn) * rs * cg.w + cb.w);
            }
        }
    }

    // final LN and store (float4-coalesced)
    float4 fg = *(const float4*)(fln_g + j);
    float4 fb = *(const float4*)(fln_b + j);
    #pragma unroll
    for (int rr = 0; rr < 4; ++rr) {
        int r = wave * 4 + rr;
        float t0 = qv[rr][0] + comb[rr][0], t1 = qv[rr][1] + comb[rr][1];
        float t2 = qv[rr][2] + comb[rr][2], t3 = qv[rr][3] + comb[rr][3];
        float s1 = wred(t0 + t1 + t2 + t3);
        float s2 = wred(t0*t0 + t1*t1 + t2*t2 + t3*t3);
        float mn = s1 * (1.f / 256.f);
        float vr = s2 * (1.f / 256.f) - mn * mn;
        float rs = rsqrtf(vr + 1e-5f);
        float4 ov;
        ov.x = (t0 - mn) * rs * fg.x + fb.x;
        ov.y = (t1 - mn) * rs * fg.y + fb.y;
        ov.z = (t2 - mn) * rs * fg.z + fb.z;
        ov.w = (t3 - mn) * rs * fg.w + fb.w;
        *(float4*)(out + (size_t)(b0 + r) * 256 + j) = ov;
    }
}

extern "C" void kernel_launch(void* const* d_in, const int* in_sizes, int n_in,
                              void* d_out, int out_size, void* d_ws, size_t ws_size,
                              hipStream_t stream) {
    const float* x    = (const float*)d_in[0];
    const float* sWi  = (const float*)d_in[1];
    const float* sbi  = (const float*)d_in[2];
    const float* sWo  = (const float*)d_in[3];
    const float* sbo  = (const float*)d_in[4];
    const float* cWi  = (const float*)d_in[5];
    const float* cbi  = (const float*)d_in[6];
    const float* cWo  = (const float*)d_in[7];
    const float* cbo  = (const float*)d_in[8];
    const float* clng = (const float*)d_in[9];
    const float* clnb = (const float*)d_in[10];
    const float* glng = (const float*)d_in[11];
    const float* glnb = (const float*)d_in[12];
    const float* gW   = (const float*)d_in[13];
    const float* gb   = (const float*)d_in[14];
    const float* flng = (const float*)d_in[15];
    const float* flnb = (const float*)d_in[16];
    const int* midx   = (const int*)d_in[17];
    float* out        = (float*)d_out;

    char* ws = (char*)d_ws;
    unsigned short* WT = (unsigned short*)ws;         // 5*256*256*2 = 655360 B (fragment order)
    float* BF          = (float*)(ws + 655360);       // 5*256*4 = 5120 B  (total 660480 B)

    k_fuse<<<dim3(64, 5), 256, 0, stream>>>(sWi, sbi, sWo, sbo, cWi, cbi, cWo, cbo, WT, BF);
    k_main<<<512, 512, 0, stream>>>(x, WT, BF, clng, clnb, glng, glnb, gW, gb, flng, flnb, midx, out);
}